// Round 1
// baseline (37.459 us; speedup 1.0000x reference)
//
#include <hip/hip_runtime.h>
#include <math.h>

#define NC    1000
#define DIM   2048
#define NBATCH 8192

// ws layout (4-byte units):
// [0,1024)      counts (int)
// [1024,2048)   cursor (int)
// [2048,3072)   offsets (int)
// [3072,11264)  rowidx (int, 8192)
// [11264,12288) loss partials (float, per class)

__global__ void k_hist(const int* __restrict__ y, int* __restrict__ counts) {
    int i = blockIdx.x * blockDim.x + threadIdx.x;
    if (i < NBATCH) atomicAdd(&counts[y[i]], 1);
}

__global__ void k_scan(const int* __restrict__ counts, int* __restrict__ offsets) {
    __shared__ int s[1024];
    int t = threadIdx.x;
    int v = (t < NC) ? counts[t] : 0;
    s[t] = v;
    __syncthreads();
    for (int off = 1; off < 1024; off <<= 1) {
        int add = (t >= off) ? s[t - off] : 0;
        __syncthreads();
        s[t] += add;
        __syncthreads();
    }
    if (t < NC) offsets[t] = s[t] - v;   // exclusive prefix
}

__global__ void k_scatter(const int* __restrict__ y, const int* __restrict__ offsets,
                          int* __restrict__ cursor, int* __restrict__ rowidx) {
    int i = blockIdx.x * blockDim.x + threadIdx.x;
    if (i < NBATCH) {
        int c = y[i];
        int pos = atomicAdd(&cursor[c], 1);
        rowidx[offsets[c] + pos] = i;
    }
}

// One block per class: gather its rows, accumulate sums + loss partial, emit grad.
__global__ __launch_bounds__(256) void k_main(
        const float* __restrict__ feat, const float* __restrict__ centers,
        const int* __restrict__ counts, const int* __restrict__ offsets,
        const int* __restrict__ rowidx,
        float* __restrict__ grad_out,      // d_out + 1 (NOT 16B aligned)
        float* __restrict__ partials) {
    int c = blockIdx.x;
    int t = threadIdx.x;
    int n = counts[c];
    int off = offsets[c];

    // each thread owns cols [4t,4t+4) and [1024+4t, 1024+4t+4)
    const float4* cen = (const float4*)(centers + (size_t)c * DIM);
    float4 c0 = cen[t];
    float4 c1 = cen[t + 256];

    float4 a0 = make_float4(0.f, 0.f, 0.f, 0.f);
    float4 a1 = make_float4(0.f, 0.f, 0.f, 0.f);
    float lsum = 0.f;

    for (int r = 0; r < n; ++r) {
        int row = rowidx[off + r];
        const float4* fp = (const float4*)(feat + (size_t)row * DIM);
        float4 v0 = fp[t];
        float4 v1 = fp[t + 256];
        a0.x += v0.x; a0.y += v0.y; a0.z += v0.z; a0.w += v0.w;
        a1.x += v1.x; a1.y += v1.y; a1.z += v1.z; a1.w += v1.w;
        float d;
        d = v0.x - c0.x; lsum += d * d;
        d = v0.y - c0.y; lsum += d * d;
        d = v0.z - c0.z; lsum += d * d;
        d = v0.w - c0.w; lsum += d * d;
        d = v1.x - c1.x; lsum += d * d;
        d = v1.y - c1.y; lsum += d * d;
        d = v1.z - c1.z; lsum += d * d;
        d = v1.w - c1.w; lsum += d * d;
    }

    float4 g0 = make_float4(0.f, 0.f, 0.f, 0.f);
    float4 g1 = make_float4(0.f, 0.f, 0.f, 0.f);
    if (n > 0) {
        float inv = 1.0f / (float)n;
        float coeff = (float)n / (1.0f + (float)n);
        g0.x = coeff * (c0.x - a0.x * inv);
        g0.y = coeff * (c0.y - a0.y * inv);
        g0.z = coeff * (c0.z - a0.z * inv);
        g0.w = coeff * (c0.w - a0.w * inv);
        g1.x = coeff * (c1.x - a1.x * inv);
        g1.y = coeff * (c1.y - a1.y * inv);
        g1.z = coeff * (c1.z - a1.z * inv);
        g1.w = coeff * (c1.w - a1.w * inv);
    }
    // grad_out is misaligned by 1 float (loss scalar precedes it) -> scalar stores.
    float* go = grad_out + (size_t)c * DIM;
    int d0 = 4 * t;
    go[d0 + 0] = g0.x; go[d0 + 1] = g0.y; go[d0 + 2] = g0.z; go[d0 + 3] = g0.w;
    int d1 = 1024 + 4 * t;
    go[d1 + 0] = g1.x; go[d1 + 1] = g1.y; go[d1 + 2] = g1.z; go[d1 + 3] = g1.w;

    // block-reduce lsum (deterministic per class)
    for (int sh = 32; sh > 0; sh >>= 1) lsum += __shfl_down(lsum, sh);
    __shared__ float red[4];
    if ((t & 63) == 0) red[t >> 6] = lsum;
    __syncthreads();
    if (t == 0) partials[c] = red[0] + red[1] + red[2] + red[3];
}

__global__ void k_loss(const float* __restrict__ partials, float* __restrict__ out) {
    __shared__ float s[256];
    int t = threadIdx.x;
    float v = 0.f;
    for (int i = t; i < NC; i += 256) v += partials[i];
    s[t] = v;
    __syncthreads();
    for (int off = 128; off > 0; off >>= 1) {
        if (t < off) s[t] += s[t + off];
        __syncthreads();
    }
    if (t == 0) out[0] = 0.5f * sqrtf(s[0]) / (float)NBATCH;
}

extern "C" void kernel_launch(void* const* d_in, const int* in_sizes, int n_in,
                              void* d_out, int out_size, void* d_ws, size_t ws_size,
                              hipStream_t stream) {
    const int*   y       = (const int*)d_in[0];
    const float* feat    = (const float*)d_in[1];
    const float* centers = (const float*)d_in[2];
    float* out = (float*)d_out;

    int* counts   = (int*)d_ws;
    int* cursor   = counts + 1024;
    int* offsets  = cursor + 1024;
    int* rowidx   = offsets + 1024;
    float* partials = (float*)(rowidx + 8192);

    // zero counts + cursor each call (harness does not re-poison between replays)
    hipMemsetAsync(d_ws, 0, 2048 * sizeof(int), stream);

    k_hist   <<<(NBATCH + 255) / 256, 256, 0, stream>>>(y, counts);
    k_scan   <<<1, 1024, 0, stream>>>(counts, offsets);
    k_scatter<<<(NBATCH + 255) / 256, 256, 0, stream>>>(y, offsets, cursor, rowidx);
    k_main   <<<NC, 256, 0, stream>>>(feat, centers, counts, offsets, rowidx,
                                      out + 1, partials);
    k_loss   <<<1, 256, 0, stream>>>(partials, out);
}

// Round 2
// 26.121 us; speedup vs baseline: 1.4341x; 1.4341x over previous
//
#include <hip/hip_runtime.h>
#include <math.h>

#define NC     1000
#define DIM    2048
#define NBATCH 8192

// One block per class. 512 threads; thread t owns cols [4t, 4t+4).
// Scans y (L2-resident, 32 KB) to find its rows, gathers feat rows once,
// producing per-class sum (-> grad) and squared-diff loss partial.
__global__ __launch_bounds__(512) void k_main(
        const int*   __restrict__ y,
        const float* __restrict__ feat,
        const float* __restrict__ centers,
        float* __restrict__ grad_out,     // d_out + 1 (4B-aligned only)
        float* __restrict__ partials) {
    const int c = blockIdx.x;
    const int t = threadIdx.x;
    const int col = t * 4;

    const float4 cen = *(const float4*)(centers + (size_t)c * DIM + col);

    __shared__ int sidx[NBATCH];   // 32 KB: worst-case all rows in one class
    __shared__ int scur;
    if (t == 0) scur = 0;
    __syncthreads();

    // coalesced scan of y; append matching row indices (order nondeterministic,
    // harmless: only affects float accumulation order)
    for (int j = t; j < NBATCH; j += 512) {
        if (y[j] == c) sidx[atomicAdd(&scur, 1)] = j;
    }
    __syncthreads();
    const int n = scur;

    float4 acc = make_float4(0.f, 0.f, 0.f, 0.f);
    float lsum = 0.f;

    int r = 0;
    for (; r + 4 <= n; r += 4) {
        int i0 = sidx[r], i1 = sidx[r+1], i2 = sidx[r+2], i3 = sidx[r+3];
        float4 v0 = *(const float4*)(feat + (size_t)i0 * DIM + col);
        float4 v1 = *(const float4*)(feat + (size_t)i1 * DIM + col);
        float4 v2 = *(const float4*)(feat + (size_t)i2 * DIM + col);
        float4 v3 = *(const float4*)(feat + (size_t)i3 * DIM + col);
        acc.x += v0.x + v1.x + v2.x + v3.x;
        acc.y += v0.y + v1.y + v2.y + v3.y;
        acc.z += v0.z + v1.z + v2.z + v3.z;
        acc.w += v0.w + v1.w + v2.w + v3.w;
        float d;
        d = v0.x - cen.x; lsum += d*d;  d = v0.y - cen.y; lsum += d*d;
        d = v0.z - cen.z; lsum += d*d;  d = v0.w - cen.w; lsum += d*d;
        d = v1.x - cen.x; lsum += d*d;  d = v1.y - cen.y; lsum += d*d;
        d = v1.z - cen.z; lsum += d*d;  d = v1.w - cen.w; lsum += d*d;
        d = v2.x - cen.x; lsum += d*d;  d = v2.y - cen.y; lsum += d*d;
        d = v2.z - cen.z; lsum += d*d;  d = v2.w - cen.w; lsum += d*d;
        d = v3.x - cen.x; lsum += d*d;  d = v3.y - cen.y; lsum += d*d;
        d = v3.z - cen.z; lsum += d*d;  d = v3.w - cen.w; lsum += d*d;
    }
    for (; r < n; ++r) {
        int i0 = sidx[r];
        float4 v0 = *(const float4*)(feat + (size_t)i0 * DIM + col);
        acc.x += v0.x; acc.y += v0.y; acc.z += v0.z; acc.w += v0.w;
        float d;
        d = v0.x - cen.x; lsum += d*d;  d = v0.y - cen.y; lsum += d*d;
        d = v0.z - cen.z; lsum += d*d;  d = v0.w - cen.w; lsum += d*d;
    }

    // grad = coeff * (centers - mean); coeff = n/(1+n); zero when n == 0
    float4 g = make_float4(0.f, 0.f, 0.f, 0.f);
    if (n > 0) {
        float fn = (float)n;
        float inv = 1.0f / fn;
        float coeff = fn / (1.0f + fn);
        g.x = coeff * (cen.x - acc.x * inv);
        g.y = coeff * (cen.y - acc.y * inv);
        g.z = coeff * (cen.z - acc.z * inv);
        g.w = coeff * (cen.w - acc.w * inv);
    }
    float* go = grad_out + (size_t)c * DIM + col;   // 4B-aligned -> scalar stores
    go[0] = g.x; go[1] = g.y; go[2] = g.z; go[3] = g.w;

    // block-reduce lsum (8 waves)
    for (int sh = 32; sh > 0; sh >>= 1) lsum += __shfl_down(lsum, sh);
    __shared__ float red[8];
    if ((t & 63) == 0) red[t >> 6] = lsum;
    __syncthreads();
    if (t == 0) {
        float s = 0.f;
        for (int k = 0; k < 8; ++k) s += red[k];
        partials[c] = s;
    }
}

__global__ void k_loss(const float* __restrict__ partials, float* __restrict__ out) {
    __shared__ float s[256];
    int t = threadIdx.x;
    float v = 0.f;
    for (int i = t; i < NC; i += 256) v += partials[i];
    s[t] = v;
    __syncthreads();
    for (int off = 128; off > 0; off >>= 1) {
        if (t < off) s[t] += s[t + off];
        __syncthreads();
    }
    if (t == 0) out[0] = 0.5f * sqrtf(s[0]) / (float)NBATCH;
}

extern "C" void kernel_launch(void* const* d_in, const int* in_sizes, int n_in,
                              void* d_out, int out_size, void* d_ws, size_t ws_size,
                              hipStream_t stream) {
    const int*   y       = (const int*)d_in[0];
    const float* feat    = (const float*)d_in[1];
    const float* centers = (const float*)d_in[2];
    float* out = (float*)d_out;
    float* partials = (float*)d_ws;   // 1000 floats, fully rewritten each call

    k_main<<<NC, 512, 0, stream>>>(y, feat, centers, out + 1, partials);
    k_loss<<<1, 256, 0, stream>>>(partials, out);
}

// Round 4
// 24.519 us; speedup vs baseline: 1.5278x; 1.0653x over previous
//
#include <hip/hip_runtime.h>
#include <math.h>

#define NC     1000
#define NBLK   2000     // 2 column-half blocks per class
#define DIM    2048
#define HALF   1024
#define NBATCH 8192

typedef float  f32x4 __attribute__((ext_vector_type(4)));
typedef int    i32x4 __attribute__((ext_vector_type(4)));

// Grid: 2000 blocks = 1000 classes x 2 column halves; 256 threads.
// Thread t of block (c,h) owns cols h*1024 + [4t, 4t+4).
// Each block scans y (L2-resident) for its class's rows, gathers feat rows
// once (nontemporal), producing per-class sum -> grad half + loss partial.
__global__ __launch_bounds__(256) void k_main(
        const int*   __restrict__ y,
        const float* __restrict__ feat,
        const float* __restrict__ centers,
        float* __restrict__ grad_out,     // d_out + 1 (4B-aligned only)
        float* __restrict__ partials) {   // [2000]
    const int c = blockIdx.x >> 1;
    const int h = blockIdx.x & 1;
    const int t = threadIdx.x;
    const int col = h * HALF + t * 4;

    const f32x4 cen = *(const f32x4*)(centers + (size_t)c * DIM + col);

    __shared__ unsigned short sidx[NBATCH];   // 16 KB worst case
    __shared__ int scur;
    if (t == 0) scur = 0;
    __syncthreads();

    // vectorized scan of y: 8192 ints as 2048 int4, 8 per thread
    const i32x4* y4 = (const i32x4*)y;
    for (int j = t; j < NBATCH / 4; j += 256) {
        i32x4 v = y4[j];
        int base = 4 * j;
        if (v.x == c) sidx[atomicAdd(&scur, 1)] = (unsigned short)(base + 0);
        if (v.y == c) sidx[atomicAdd(&scur, 1)] = (unsigned short)(base + 1);
        if (v.z == c) sidx[atomicAdd(&scur, 1)] = (unsigned short)(base + 2);
        if (v.w == c) sidx[atomicAdd(&scur, 1)] = (unsigned short)(base + 3);
    }
    __syncthreads();
    const int n = scur;

    f32x4 acc = (f32x4)(0.f);
    float lsum = 0.f;

    int r = 0;
    for (; r + 4 <= n; r += 4) {
        int i0 = sidx[r], i1 = sidx[r+1], i2 = sidx[r+2], i3 = sidx[r+3];
        f32x4 v0 = __builtin_nontemporal_load((const f32x4*)(feat + (size_t)i0 * DIM + col));
        f32x4 v1 = __builtin_nontemporal_load((const f32x4*)(feat + (size_t)i1 * DIM + col));
        f32x4 v2 = __builtin_nontemporal_load((const f32x4*)(feat + (size_t)i2 * DIM + col));
        f32x4 v3 = __builtin_nontemporal_load((const f32x4*)(feat + (size_t)i3 * DIM + col));
        acc += v0 + v1 + v2 + v3;
        f32x4 d0 = v0 - cen, d1 = v1 - cen, d2 = v2 - cen, d3 = v3 - cen;
        f32x4 sq = d0 * d0 + d1 * d1 + d2 * d2 + d3 * d3;
        lsum += sq.x + sq.y + sq.z + sq.w;
    }
    for (; r < n; ++r) {
        int i0 = sidx[r];
        f32x4 v0 = __builtin_nontemporal_load((const f32x4*)(feat + (size_t)i0 * DIM + col));
        acc += v0;
        f32x4 d0 = v0 - cen;
        f32x4 sq = d0 * d0;
        lsum += sq.x + sq.y + sq.z + sq.w;
    }

    // grad = coeff * (centers - mean); coeff = n/(1+n); zero when n == 0
    f32x4 g = (f32x4)(0.f);
    if (n > 0) {
        float fn = (float)n;
        float inv = 1.0f / fn;
        float coeff = fn / (1.0f + fn);
        g = coeff * (cen - acc * inv);
    }
    float* go = grad_out + (size_t)c * DIM + col;   // 4B-aligned -> scalar stores
    __builtin_nontemporal_store(g.x, go + 0);
    __builtin_nontemporal_store(g.y, go + 1);
    __builtin_nontemporal_store(g.z, go + 2);
    __builtin_nontemporal_store(g.w, go + 3);

    // block-reduce lsum (4 waves)
    for (int sh = 32; sh > 0; sh >>= 1) lsum += __shfl_down(lsum, sh);
    __shared__ float red[4];
    if ((t & 63) == 0) red[t >> 6] = lsum;
    __syncthreads();
    if (t == 0) partials[blockIdx.x] = red[0] + red[1] + red[2] + red[3];
}

__global__ void k_loss(const float* __restrict__ partials, float* __restrict__ out) {
    __shared__ float s[256];
    int t = threadIdx.x;
    float v = 0.f;
    for (int i = t; i < NBLK; i += 256) v += partials[i];
    s[t] = v;
    __syncthreads();
    for (int off = 128; off > 0; off >>= 1) {
        if (t < off) s[t] += s[t + off];
        __syncthreads();
    }
    if (t == 0) out[0] = 0.5f * sqrtf(s[0]) / (float)NBATCH;
}

extern "C" void kernel_launch(void* const* d_in, const int* in_sizes, int n_in,
                              void* d_out, int out_size, void* d_ws, size_t ws_size,
                              hipStream_t stream) {
    const int*   y       = (const int*)d_in[0];
    const float* feat    = (const float*)d_in[1];
    const float* centers = (const float*)d_in[2];
    float* out = (float*)d_out;
    float* partials = (float*)d_ws;   // 2000 floats, fully rewritten each call

    k_main<<<NBLK, 256, 0, stream>>>(y, feat, centers, out + 1, partials);
    k_loss<<<1, 256, 0, stream>>>(partials, out);
}